// Round 5
// baseline (2249.980 us; speedup 1.0000x reference)
//
#include <hip/hip_runtime.h>
#include <hip/hip_bf16.h>

#define WPB 4          // waves per block (256 threads)
#define SCAN_EPB 1024  // elements per scan block (256 thr x 4)

// ---------------- encoders ----------------
// out = tanh(x @ W1^T + b1) @ W2^T + b2. 4 rows per wave iteration.
template<int IN_F>
__global__ __launch_bounds__(256) void encoder_kernel(
    const float* __restrict__ x,
    const float* __restrict__ W1, const float* __restrict__ b1,
    const float* __restrict__ W2, const float* __restrict__ b2,
    float* __restrict__ out, int n_rows) {
  __shared__ float sW1[64 * IN_F];
  __shared__ float sW2T[64 * 65];   // sW2T[k*65+o] = W2[o][k]
  __shared__ float sb1[64];
  __shared__ float sb2[64];
  int t = threadIdx.x;
  for (int i = t; i < 64 * IN_F; i += 256) sW1[i] = W1[i];
  for (int i = t; i < 64 * 64; i += 256) {
    int o = i >> 6, k = i & 63;
    sW2T[k * 65 + o] = W2[i];
  }
  if (t < 64) { sb1[t] = b1[t]; sb2[t] = b2[t]; }
  __syncthreads();

  int wave = t >> 6, lane = t & 63;
  int stride = gridDim.x * WPB * 4;
  const int total = n_rows * IN_F;
  for (int rowb = (blockIdx.x * WPB + wave) * 4; rowb < n_rows; rowb += stride) {
    // 4 rows' inputs are 4*IN_F contiguous floats; lanes 0..4*IN_F-1 load them
    float xl = 0.0f;
    if (lane < 4 * IN_F) {
      int idx = rowb * IN_F + lane;
      if (idx < total) xl = x[idx];
    }
    float h0 = sb1[lane], h1 = h0, h2 = h0, h3 = h0;
#pragma unroll
    for (int j = 0; j < IN_F; ++j) {
      float w = sW1[lane * IN_F + j];
      h0 += w * __shfl(xl, 0 * IN_F + j, 64);
      h1 += w * __shfl(xl, 1 * IN_F + j, 64);
      h2 += w * __shfl(xl, 2 * IN_F + j, 64);
      h3 += w * __shfl(xl, 3 * IN_F + j, 64);
    }
    h0 = tanhf(h0); h1 = tanhf(h1); h2 = tanhf(h2); h3 = tanhf(h3);

    float o0 = sb2[lane], o1 = o0, o2 = o0, o3 = o0;
#pragma unroll
    for (int i = 0; i < 64; ++i) {
      float w = sW2T[i * 65 + lane];
      o0 += w * __shfl(h0, i, 64);
      o1 += w * __shfl(h1, i, 64);
      o2 += w * __shfl(h2, i, 64);
      o3 += w * __shfl(h3, i, 64);
    }
    out[(size_t)rowb * 64 + lane] = o0;
    if (rowb + 1 < n_rows) out[(size_t)(rowb + 1) * 64 + lane] = o1;
    if (rowb + 2 < n_rows) out[(size_t)(rowb + 2) * 64 + lane] = o2;
    if (rowb + 3 < n_rows) out[(size_t)(rowb + 3) * 64 + lane] = o3;
  }
}

// ---------------- CSR build ----------------
__global__ __launch_bounds__(256) void hist_kernel(
    const int* __restrict__ ev, const int* __restrict__ ec,
    int* __restrict__ cur_v, int* __restrict__ cur_c, int n_edges) {
  int e = blockIdx.x * 256 + threadIdx.x;
  if (e >= n_edges) return;
  atomicAdd(&cur_v[ev[e]], 1);
  atomicAdd(&cur_c[ec[e]], 1);
}

__global__ __launch_bounds__(256) void scan_blocks_kernel(
    const int* __restrict__ in, int* __restrict__ out,
    int* __restrict__ bsums, int n) {
  __shared__ int s[256];
  int t = threadIdx.x;
  int base = blockIdx.x * SCAN_EPB + t * 4;
  int v[4]; int local = 0;
#pragma unroll
  for (int j = 0; j < 4; ++j) {
    int idx = base + j;
    v[j] = (idx < n) ? in[idx] : 0;
    local += v[j];
  }
  s[t] = local;
  __syncthreads();
  for (int off = 1; off < 256; off <<= 1) {
    int val = (t >= off) ? s[t - off] : 0;
    __syncthreads();
    s[t] += val;
    __syncthreads();
  }
  int run = s[t] - local;
#pragma unroll
  for (int j = 0; j < 4; ++j) {
    int idx = base + j;
    if (idx < n) out[idx] = run;
    run += v[j];
  }
  if (t == 255) bsums[blockIdx.x] = s[255];
}

__global__ __launch_bounds__(256) void scan_sums_kernel(int* __restrict__ bsums, int nb) {
  __shared__ int s[256];
  int t = threadIdx.x;
  int base = t * 4;
  int v[4]; int local = 0;
#pragma unroll
  for (int j = 0; j < 4; ++j) {
    int idx = base + j;
    v[j] = (idx < nb) ? bsums[idx] : 0;
    local += v[j];
  }
  s[t] = local;
  __syncthreads();
  for (int off = 1; off < 256; off <<= 1) {
    int val = (t >= off) ? s[t - off] : 0;
    __syncthreads();
    s[t] += val;
    __syncthreads();
  }
  int run = s[t] - local;
#pragma unroll
  for (int j = 0; j < 4; ++j) {
    int idx = base + j;
    if (idx < nb) bsums[idx] = run;
    run += v[j];
  }
}

__global__ __launch_bounds__(256) void scan_add_kernel(
    int* __restrict__ out, const int* __restrict__ bsums, int n, int total) {
  int t = threadIdx.x;
  int base = blockIdx.x * SCAN_EPB + t * 4;
  int add = bsums[blockIdx.x];
#pragma unroll
  for (int j = 0; j < 4; ++j) {
    int idx = base + j;
    if (idx < n) out[idx] += add;
  }
  if (blockIdx.x == 0 && t == 0) out[n] = total;
}

__global__ __launch_bounds__(256) void place_kernel(
    const int* __restrict__ ev, const int* __restrict__ ec,
    const int* __restrict__ rp_v, const int* __restrict__ rp_c,
    int* __restrict__ cur_v, int* __restrict__ cur_c,
    int* __restrict__ esrc_v, int* __restrict__ esrc_c, int n_edges) {
  int e = blockIdx.x * 256 + threadIdx.x;
  if (e >= n_edges) return;
  int v = ev[e], c = ec[e];
  int pc = rp_c[c] + atomicAdd(&cur_c[c], 1);
  esrc_c[pc] = v;
  int pv = rp_v[v] + atomicAdd(&cur_v[v], 1);
  esrc_v[pv] = c;
}

// ---------------- fused aggregate + linear + tanh (+ optional readout) ----------------
// 4 rows per wave: interleaved gather (8 loads in flight), shared-W matvec.
template<bool RO>
__global__ __launch_bounds__(256) void fused_update_kernel(
    float* __restrict__ hdst, const float* __restrict__ hsrc,
    const int* __restrict__ rp, const int* __restrict__ esrc,
    const float* __restrict__ W, const float* __restrict__ b,
    const float* __restrict__ Wro, const float* __restrict__ bro,
    float* __restrict__ scores, int n_rows) {
  __shared__ float sWT[64 * 65];  // sWT[k*65+o] = W[o][k]
  __shared__ float sb[64];
  __shared__ float sWro[64];
  int t = threadIdx.x;
  for (int i = t; i < 64 * 64; i += 256) {
    int o = i >> 6, k = i & 63;
    sWT[k * 65 + o] = W[i];
  }
  if (t < 64) { sb[t] = b[t]; if (RO) sWro[t] = Wro[t]; }
  __syncthreads();

  int wave = t >> 6, lane = t & 63;
  float brov = RO ? bro[0] : 0.0f;
  int stride = gridDim.x * WPB * 4;
  for (int rowb = (blockIdx.x * WPB + wave) * 4; rowb < n_rows; rowb += stride) {
    int r0 = rowb;
    int r1 = (rowb + 1 < n_rows) ? rowb + 1 : n_rows - 1;
    int r2 = (rowb + 2 < n_rows) ? rowb + 2 : n_rows - 1;
    int r3 = (rowb + 3 < n_rows) ? rowb + 3 : n_rows - 1;
    int p0 = rp[r0], e0 = rp[r0 + 1];
    int p1 = rp[r1], e1 = rp[r1 + 1];
    int p2 = rp[r2], e2 = rp[r2 + 1];
    int p3 = rp[r3], e3 = rp[r3 + 1];
    float deg0 = (float)(e0 - p0), deg1 = (float)(e1 - p1);
    float deg2 = (float)(e2 - p2), deg3 = (float)(e3 - p3);
    float a0 = 0.f, a1 = 0.f, a2 = 0.f, a3 = 0.f;

    // main loop: 2 edges per row, 8 independent loads per iteration (uniform cond)
    while (p0 + 1 < e0 && p1 + 1 < e1 && p2 + 1 < e2 && p3 + 1 < e3) {
      int s0a = esrc[p0], s0b = esrc[p0 + 1];
      int s1a = esrc[p1], s1b = esrc[p1 + 1];
      int s2a = esrc[p2], s2b = esrc[p2 + 1];
      int s3a = esrc[p3], s3b = esrc[p3 + 1];
      float t0a = hsrc[(size_t)s0a * 64 + lane], t0b = hsrc[(size_t)s0b * 64 + lane];
      float t1a = hsrc[(size_t)s1a * 64 + lane], t1b = hsrc[(size_t)s1b * 64 + lane];
      float t2a = hsrc[(size_t)s2a * 64 + lane], t2b = hsrc[(size_t)s2b * 64 + lane];
      float t3a = hsrc[(size_t)s3a * 64 + lane], t3b = hsrc[(size_t)s3b * 64 + lane];
      a0 += t0a; a0 += t0b; a1 += t1a; a1 += t1b;
      a2 += t2a; a2 += t2b; a3 += t3a; a3 += t3b;
      p0 += 2; p1 += 2; p2 += 2; p3 += 2;
    }
    // predicated merged drain: straight-line, 4 loads per iteration (uniform cond)
    while (p0 < e0 || p1 < e1 || p2 < e2 || p3 < e3) {
      int q0 = (p0 < e0) ? esrc[p0] : 0;
      int q1 = (p1 < e1) ? esrc[p1] : 0;
      int q2 = (p2 < e2) ? esrc[p2] : 0;
      int q3 = (p3 < e3) ? esrc[p3] : 0;
      float m0 = (p0 < e0) ? 1.f : 0.f;
      float m1 = (p1 < e1) ? 1.f : 0.f;
      float m2 = (p2 < e2) ? 1.f : 0.f;
      float m3 = (p3 < e3) ? 1.f : 0.f;
      float t0 = hsrc[(size_t)q0 * 64 + lane];
      float t1 = hsrc[(size_t)q1 * 64 + lane];
      float t2 = hsrc[(size_t)q2 * 64 + lane];
      float t3 = hsrc[(size_t)q3 * 64 + lane];
      a0 += m0 * t0; a1 += m1 * t1; a2 += m2 * t2; a3 += m3 * t3;
      p0 = (p0 < e0) ? p0 + 1 : p0;
      p1 = (p1 < e1) ? p1 + 1 : p1;
      p2 = (p2 < e2) ? p2 + 1 : p2;
      p3 = (p3 < e3) ? p3 + 1 : p3;
    }

    float v0 = hdst[(size_t)r0 * 64 + lane] + sb[lane] * deg0;
    float v1 = hdst[(size_t)r1 * 64 + lane] + sb[lane] * deg1;
    float v2 = hdst[(size_t)r2 * 64 + lane] + sb[lane] * deg2;
    float v3 = hdst[(size_t)r3 * 64 + lane] + sb[lane] * deg3;
#pragma unroll
    for (int i = 0; i < 64; ++i) {
      float w = sWT[i * 65 + lane];
      v0 += w * __shfl(a0, i, 64);
      v1 += w * __shfl(a1, i, 64);
      v2 += w * __shfl(a2, i, 64);
      v3 += w * __shfl(a3, i, 64);
    }
    v0 = tanhf(v0); v1 = tanhf(v1); v2 = tanhf(v2); v3 = tanhf(v3);
    if (RO) {
      float rv0 = v0 * sWro[lane], rv1 = v1 * sWro[lane];
      float rv2 = v2 * sWro[lane], rv3 = v3 * sWro[lane];
#pragma unroll
      for (int off = 32; off > 0; off >>= 1) {
        rv0 += __shfl_xor(rv0, off, 64);
        rv1 += __shfl_xor(rv1, off, 64);
        rv2 += __shfl_xor(rv2, off, 64);
        rv3 += __shfl_xor(rv3, off, 64);
      }
      if (lane == 0) {
        scores[rowb] = rv0 + brov;
        if (rowb + 1 < n_rows) scores[rowb + 1] = rv1 + brov;
        if (rowb + 2 < n_rows) scores[rowb + 2] = rv2 + brov;
        if (rowb + 3 < n_rows) scores[rowb + 3] = rv3 + brov;
      }
    } else {
      hdst[(size_t)rowb * 64 + lane] = v0;
      if (rowb + 1 < n_rows) hdst[(size_t)(rowb + 1) * 64 + lane] = v1;
      if (rowb + 2 < n_rows) hdst[(size_t)(rowb + 2) * 64 + lane] = v2;
      if (rowb + 3 < n_rows) hdst[(size_t)(rowb + 3) * 64 + lane] = v3;
    }
  }
}

static inline int rowgrid4(int n) {
  int want = (n + WPB * 4 - 1) / (WPB * 4);
  return want < 2048 ? want : 2048;
}

extern "C" void kernel_launch(void* const* d_in, const int* in_sizes, int n_in,
                              void* d_out, int out_size, void* d_ws, size_t ws_size,
                              hipStream_t stream) {
  const float* vf    = (const float*)d_in[0];
  const float* cf    = (const float*)d_in[1];
  const int*   ev    = (const int*)d_in[2];
  const int*   ec    = (const int*)d_in[3];
  const float* W_ve1 = (const float*)d_in[4];
  const float* b_ve1 = (const float*)d_in[5];
  const float* W_ve2 = (const float*)d_in[6];
  const float* b_ve2 = (const float*)d_in[7];
  const float* W_ce1 = (const float*)d_in[8];
  const float* b_ce1 = (const float*)d_in[9];
  const float* W_ce2 = (const float*)d_in[10];
  const float* b_ce2 = (const float*)d_in[11];
  const float* W_v2c = (const float*)d_in[12];
  const float* b_v2c = (const float*)d_in[13];
  const float* W_c2v = (const float*)d_in[14];
  const float* b_c2v = (const float*)d_in[15];
  const float* W_ro  = (const float*)d_in[16];
  const float* b_ro  = (const float*)d_in[17];

  const int n_vars  = in_sizes[0] / 7;
  const int n_cons  = in_sizes[1] / 5;
  const int n_edges = in_sizes[2];
  const int R       = in_sizes[12] / (64 * 64);

  char* p = (char*)d_ws;
  float* h_var  = (float*)p; p += (size_t)n_vars * 64 * 4;
  float* h_con  = (float*)p; p += (size_t)n_cons * 64 * 4;
  int*   rp_v   = (int*)p;   p += (size_t)(n_vars + 1) * 4;
  int*   rp_c   = (int*)p;   p += (size_t)(n_cons + 1) * 4;
  int*   cur_v  = (int*)p;   p += (size_t)n_vars * 4;
  int*   cur_c  = (int*)p;   p += (size_t)n_cons * 4;
  int*   esrc_v = (int*)p;   p += (size_t)n_edges * 4;
  int*   esrc_c = (int*)p;   p += (size_t)n_edges * 4;
  int*   bsums  = (int*)p;   p += 1024 * 4;

  const int nb_v = (n_vars + SCAN_EPB - 1) / SCAN_EPB;
  const int nb_c = (n_cons + SCAN_EPB - 1) / SCAN_EPB;

  hipMemsetAsync(cur_v, 0, (size_t)n_vars * 4, stream);
  hipMemsetAsync(cur_c, 0, (size_t)n_cons * 4, stream);
  hist_kernel<<<(n_edges + 255) / 256, 256, 0, stream>>>(ev, ec, cur_v, cur_c, n_edges);

  scan_blocks_kernel<<<nb_v, 256, 0, stream>>>(cur_v, rp_v, bsums, n_vars);
  scan_sums_kernel<<<1, 256, 0, stream>>>(bsums, nb_v);
  scan_add_kernel<<<nb_v, 256, 0, stream>>>(rp_v, bsums, n_vars, n_edges);
  scan_blocks_kernel<<<nb_c, 256, 0, stream>>>(cur_c, rp_c, bsums, n_cons);
  scan_sums_kernel<<<1, 256, 0, stream>>>(bsums, nb_c);
  scan_add_kernel<<<nb_c, 256, 0, stream>>>(rp_c, bsums, n_cons, n_edges);

  hipMemsetAsync(cur_v, 0, (size_t)n_vars * 4, stream);
  hipMemsetAsync(cur_c, 0, (size_t)n_cons * 4, stream);
  place_kernel<<<(n_edges + 255) / 256, 256, 0, stream>>>(
      ev, ec, rp_v, rp_c, cur_v, cur_c, esrc_v, esrc_c, n_edges);

  encoder_kernel<7><<<rowgrid4(n_vars), 256, 0, stream>>>(
      vf, W_ve1, b_ve1, W_ve2, b_ve2, h_var, n_vars);
  encoder_kernel<5><<<rowgrid4(n_cons), 256, 0, stream>>>(
      cf, W_ce1, b_ce1, W_ce2, b_ce2, h_con, n_cons);

  for (int r = 0; r < R; ++r) {
    fused_update_kernel<false><<<rowgrid4(n_cons), 256, 0, stream>>>(
        h_con, h_var, rp_c, esrc_c,
        W_v2c + (size_t)r * 64 * 64, b_v2c + (size_t)r * 64,
        nullptr, nullptr, nullptr, n_cons);
    if (r == R - 1) {
      fused_update_kernel<true><<<rowgrid4(n_vars), 256, 0, stream>>>(
          h_var, h_con, rp_v, esrc_v,
          W_c2v + (size_t)r * 64 * 64, b_c2v + (size_t)r * 64,
          W_ro, b_ro, (float*)d_out, n_vars);
    } else {
      fused_update_kernel<false><<<rowgrid4(n_vars), 256, 0, stream>>>(
          h_var, h_con, rp_v, esrc_v,
          W_c2v + (size_t)r * 64 * 64, b_c2v + (size_t)r * 64,
          nullptr, nullptr, nullptr, n_vars);
    }
  }
}

// Round 6
// 989.427 us; speedup vs baseline: 2.2740x; 2.2740x over previous
//
#include <hip/hip_runtime.h>
#include <hip/hip_bf16.h>

#define WPB 4          // waves per block (256 threads)
#define SCAN_EPB 1024  // elements per scan block (256 thr x 4)

__device__ __forceinline__ float bcast(float v, int i) {
  return __builtin_bit_cast(float, __builtin_amdgcn_readlane(__builtin_bit_cast(int, v), i));
}

// ---------------- encoders ----------------
// out = tanh(x @ W1^T + b1) @ W2^T + b2. One row per wave; W in VGPRs, no LDS.
template<int IN_F>
__global__ __launch_bounds__(256, 3) void encoder_kernel(
    const float* __restrict__ x,
    const float* __restrict__ W1, const float* __restrict__ b1,
    const float* __restrict__ W2, const float* __restrict__ b2,
    float* __restrict__ out, int n_rows) {
  int t = threadIdx.x;
  int wave = t >> 6, lane = t & 63;

  // per-lane weight rows: lane o holds W1[o][*], W2[o][*]
  float w1reg[IN_F];
#pragma unroll
  for (int j = 0; j < IN_F; ++j) w1reg[j] = W1[lane * IN_F + j];
  float w2reg[64];
  const float4* W24 = (const float4*)(W2 + (size_t)lane * 64);
#pragma unroll
  for (int i = 0; i < 16; ++i) {
    float4 w = W24[i];
    w2reg[4 * i] = w.x; w2reg[4 * i + 1] = w.y;
    w2reg[4 * i + 2] = w.z; w2reg[4 * i + 3] = w.w;
  }
  float b1v = b1[lane], b2v = b2[lane];

  int stride = gridDim.x * WPB;
  for (int row = blockIdx.x * WPB + wave; row < n_rows; row += stride) {
    float xl = 0.0f;
    if (lane < IN_F) xl = x[(size_t)row * IN_F + lane];
    float h = b1v;
#pragma unroll
    for (int j = 0; j < IN_F; ++j) h += w1reg[j] * bcast(xl, j);
    float hid = tanhf(h);

    float o0 = b2v, o1 = 0.f, o2 = 0.f, o3 = 0.f;
#pragma unroll
    for (int i = 0; i < 64; i += 4) {
      o0 += w2reg[i]     * bcast(hid, i);
      o1 += w2reg[i + 1] * bcast(hid, i + 1);
      o2 += w2reg[i + 2] * bcast(hid, i + 2);
      o3 += w2reg[i + 3] * bcast(hid, i + 3);
    }
    out[(size_t)row * 64 + lane] = (o0 + o1) + (o2 + o3);
  }
}

// ---------------- CSR build ----------------
__global__ __launch_bounds__(256) void hist_kernel(
    const int* __restrict__ ev, const int* __restrict__ ec,
    int* __restrict__ cur_v, int* __restrict__ cur_c, int n_edges) {
  int e = blockIdx.x * 256 + threadIdx.x;
  if (e >= n_edges) return;
  atomicAdd(&cur_v[ev[e]], 1);
  atomicAdd(&cur_c[ec[e]], 1);
}

__global__ __launch_bounds__(256) void scan_blocks_kernel(
    const int* __restrict__ in, int* __restrict__ out,
    int* __restrict__ bsums, int n) {
  __shared__ int s[256];
  int t = threadIdx.x;
  int base = blockIdx.x * SCAN_EPB + t * 4;
  int v[4]; int local = 0;
#pragma unroll
  for (int j = 0; j < 4; ++j) {
    int idx = base + j;
    v[j] = (idx < n) ? in[idx] : 0;
    local += v[j];
  }
  s[t] = local;
  __syncthreads();
  for (int off = 1; off < 256; off <<= 1) {
    int val = (t >= off) ? s[t - off] : 0;
    __syncthreads();
    s[t] += val;
    __syncthreads();
  }
  int run = s[t] - local;
#pragma unroll
  for (int j = 0; j < 4; ++j) {
    int idx = base + j;
    if (idx < n) out[idx] = run;
    run += v[j];
  }
  if (t == 255) bsums[blockIdx.x] = s[255];
}

__global__ __launch_bounds__(256) void scan_sums_kernel(int* __restrict__ bsums, int nb) {
  __shared__ int s[256];
  int t = threadIdx.x;
  int base = t * 4;
  int v[4]; int local = 0;
#pragma unroll
  for (int j = 0; j < 4; ++j) {
    int idx = base + j;
    v[j] = (idx < nb) ? bsums[idx] : 0;
    local += v[j];
  }
  s[t] = local;
  __syncthreads();
  for (int off = 1; off < 256; off <<= 1) {
    int val = (t >= off) ? s[t - off] : 0;
    __syncthreads();
    s[t] += val;
    __syncthreads();
  }
  int run = s[t] - local;
#pragma unroll
  for (int j = 0; j < 4; ++j) {
    int idx = base + j;
    if (idx < nb) bsums[idx] = run;
    run += v[j];
  }
}

__global__ __launch_bounds__(256) void scan_add_kernel(
    int* __restrict__ out, const int* __restrict__ bsums, int n, int total) {
  int t = threadIdx.x;
  int base = blockIdx.x * SCAN_EPB + t * 4;
  int add = bsums[blockIdx.x];
#pragma unroll
  for (int j = 0; j < 4; ++j) {
    int idx = base + j;
    if (idx < n) out[idx] += add;
  }
  if (blockIdx.x == 0 && t == 0) out[n] = total;
}

__global__ __launch_bounds__(256) void place_kernel(
    const int* __restrict__ ev, const int* __restrict__ ec,
    const int* __restrict__ rp_v, const int* __restrict__ rp_c,
    int* __restrict__ cur_v, int* __restrict__ cur_c,
    int* __restrict__ esrc_v, int* __restrict__ esrc_c, int n_edges) {
  int e = blockIdx.x * 256 + threadIdx.x;
  if (e >= n_edges) return;
  int v = ev[e], c = ec[e];
  int pc = rp_c[c] + atomicAdd(&cur_c[c], 1);
  esrc_c[pc] = v;
  int pv = rp_v[v] + atomicAdd(&cur_v[v], 1);
  esrc_v[pv] = c;
}

// ---------------- fused aggregate + linear + tanh (+ optional readout) ----------------
// One row per wave. W held in per-lane VGPRs; broadcasts via v_readlane (no LDS).
template<bool RO>
__global__ __launch_bounds__(256, 3) void fused_update_kernel(
    float* __restrict__ hdst, const float* __restrict__ hsrc,
    const int* __restrict__ rp, const int* __restrict__ esrc,
    const float* __restrict__ W, const float* __restrict__ b,
    const float* __restrict__ Wro, const float* __restrict__ bro,
    float* __restrict__ scores, int n_rows) {
  int t = threadIdx.x;
  int wave = t >> 6, lane = t & 63;

  float wreg[64];  // lane o holds W[o][0..63]
  const float4* W4 = (const float4*)(W + (size_t)lane * 64);
#pragma unroll
  for (int i = 0; i < 16; ++i) {
    float4 w = W4[i];
    wreg[4 * i] = w.x; wreg[4 * i + 1] = w.y;
    wreg[4 * i + 2] = w.z; wreg[4 * i + 3] = w.w;
  }
  float bv = b[lane];
  float wrov = RO ? Wro[lane] : 0.0f;
  float brov = RO ? bro[0] : 0.0f;

  int stride = gridDim.x * WPB;
  for (int row = blockIdx.x * WPB + wave; row < n_rows; row += stride) {
    int p = rp[row], end = rp[row + 1];
    float deg = (float)(end - p);
    float a = 0.0f;
    // 4-wide gather: 8 independent loads in flight; wave-uniform control
    for (; p + 4 <= end; p += 4) {
      int s0 = esrc[p], s1 = esrc[p + 1], s2 = esrc[p + 2], s3 = esrc[p + 3];
      float t0 = hsrc[(size_t)s0 * 64 + lane];
      float t1 = hsrc[(size_t)s1 * 64 + lane];
      float t2 = hsrc[(size_t)s2 * 64 + lane];
      float t3 = hsrc[(size_t)s3 * 64 + lane];
      a += (t0 + t1) + (t2 + t3);
    }
    for (; p < end; ++p) a += hsrc[(size_t)esrc[p] * 64 + lane];

    float v0 = hdst[(size_t)row * 64 + lane] + bv * deg;
    float v1 = 0.f, v2 = 0.f, v3 = 0.f;
#pragma unroll
    for (int i = 0; i < 64; i += 4) {
      v0 += wreg[i]     * bcast(a, i);
      v1 += wreg[i + 1] * bcast(a, i + 1);
      v2 += wreg[i + 2] * bcast(a, i + 2);
      v3 += wreg[i + 3] * bcast(a, i + 3);
    }
    float hv = tanhf((v0 + v1) + (v2 + v3));
    if (RO) {
      float rv = hv * wrov;
#pragma unroll
      for (int off = 32; off > 0; off >>= 1) rv += __shfl_xor(rv, off, 64);
      if (lane == 0) scores[row] = rv + brov;
    } else {
      hdst[(size_t)row * 64 + lane] = hv;
    }
  }
}

static inline int rowgrid(int n) {
  int want = (n + WPB - 1) / WPB;
  return want < 2048 ? want : 2048;
}

extern "C" void kernel_launch(void* const* d_in, const int* in_sizes, int n_in,
                              void* d_out, int out_size, void* d_ws, size_t ws_size,
                              hipStream_t stream) {
  const float* vf    = (const float*)d_in[0];
  const float* cf    = (const float*)d_in[1];
  const int*   ev    = (const int*)d_in[2];
  const int*   ec    = (const int*)d_in[3];
  const float* W_ve1 = (const float*)d_in[4];
  const float* b_ve1 = (const float*)d_in[5];
  const float* W_ve2 = (const float*)d_in[6];
  const float* b_ve2 = (const float*)d_in[7];
  const float* W_ce1 = (const float*)d_in[8];
  const float* b_ce1 = (const float*)d_in[9];
  const float* W_ce2 = (const float*)d_in[10];
  const float* b_ce2 = (const float*)d_in[11];
  const float* W_v2c = (const float*)d_in[12];
  const float* b_v2c = (const float*)d_in[13];
  const float* W_c2v = (const float*)d_in[14];
  const float* b_c2v = (const float*)d_in[15];
  const float* W_ro  = (const float*)d_in[16];
  const float* b_ro  = (const float*)d_in[17];

  const int n_vars  = in_sizes[0] / 7;
  const int n_cons  = in_sizes[1] / 5;
  const int n_edges = in_sizes[2];
  const int R       = in_sizes[12] / (64 * 64);

  char* p = (char*)d_ws;
  float* h_var  = (float*)p; p += (size_t)n_vars * 64 * 4;
  float* h_con  = (float*)p; p += (size_t)n_cons * 64 * 4;
  int*   rp_v   = (int*)p;   p += (size_t)(n_vars + 1) * 4;
  int*   rp_c   = (int*)p;   p += (size_t)(n_cons + 1) * 4;
  int*   cur_v  = (int*)p;   p += (size_t)n_vars * 4;
  int*   cur_c  = (int*)p;   p += (size_t)n_cons * 4;
  int*   esrc_v = (int*)p;   p += (size_t)n_edges * 4;
  int*   esrc_c = (int*)p;   p += (size_t)n_edges * 4;
  int*   bsums  = (int*)p;   p += 1024 * 4;

  const int nb_v = (n_vars + SCAN_EPB - 1) / SCAN_EPB;
  const int nb_c = (n_cons + SCAN_EPB - 1) / SCAN_EPB;

  hipMemsetAsync(cur_v, 0, (size_t)n_vars * 4, stream);
  hipMemsetAsync(cur_c, 0, (size_t)n_cons * 4, stream);
  hist_kernel<<<(n_edges + 255) / 256, 256, 0, stream>>>(ev, ec, cur_v, cur_c, n_edges);

  scan_blocks_kernel<<<nb_v, 256, 0, stream>>>(cur_v, rp_v, bsums, n_vars);
  scan_sums_kernel<<<1, 256, 0, stream>>>(bsums, nb_v);
  scan_add_kernel<<<nb_v, 256, 0, stream>>>(rp_v, bsums, n_vars, n_edges);
  scan_blocks_kernel<<<nb_c, 256, 0, stream>>>(cur_c, rp_c, bsums, n_cons);
  scan_sums_kernel<<<1, 256, 0, stream>>>(bsums, nb_c);
  scan_add_kernel<<<nb_c, 256, 0, stream>>>(rp_c, bsums, n_cons, n_edges);

  hipMemsetAsync(cur_v, 0, (size_t)n_vars * 4, stream);
  hipMemsetAsync(cur_c, 0, (size_t)n_cons * 4, stream);
  place_kernel<<<(n_edges + 255) / 256, 256, 0, stream>>>(
      ev, ec, rp_v, rp_c, cur_v, cur_c, esrc_v, esrc_c, n_edges);

  encoder_kernel<7><<<rowgrid(n_vars), 256, 0, stream>>>(
      vf, W_ve1, b_ve1, W_ve2, b_ve2, h_var, n_vars);
  encoder_kernel<5><<<rowgrid(n_cons), 256, 0, stream>>>(
      cf, W_ce1, b_ce1, W_ce2, b_ce2, h_con, n_cons);

  for (int r = 0; r < R; ++r) {
    fused_update_kernel<false><<<rowgrid(n_cons), 256, 0, stream>>>(
        h_con, h_var, rp_c, esrc_c,
        W_v2c + (size_t)r * 64 * 64, b_v2c + (size_t)r * 64,
        nullptr, nullptr, nullptr, n_cons);
    if (r == R - 1) {
      fused_update_kernel<true><<<rowgrid(n_vars), 256, 0, stream>>>(
          h_var, h_con, rp_v, esrc_v,
          W_c2v + (size_t)r * 64 * 64, b_c2v + (size_t)r * 64,
          W_ro, b_ro, (float*)d_out, n_vars);
    } else {
      fused_update_kernel<false><<<rowgrid(n_vars), 256, 0, stream>>>(
          h_var, h_con, rp_v, esrc_v,
          W_c2v + (size_t)r * 64 * 64, b_c2v + (size_t)r * 64,
          nullptr, nullptr, nullptr, n_vars);
    }
  }
}

// Round 7
// 956.980 us; speedup vs baseline: 2.3511x; 1.0339x over previous
//
#include <hip/hip_runtime.h>
#include <hip/hip_bf16.h>
#include <hip/hip_fp16.h>

#define WPB 4          // waves per block (256 threads)
#define SCAN_EPB 1024  // elements per scan block (256 thr x 4)

__device__ __forceinline__ float bcast(float v, int i) {
  return __builtin_bit_cast(float, __builtin_amdgcn_readlane(__builtin_bit_cast(int, v), i));
}

// ---------------- encoders ----------------
// out = tanh(x @ W1^T + b1) @ W2^T + b2. One row per wave; W in VGPRs; f16 output.
template<int IN_F>
__global__ __launch_bounds__(256, 4) void encoder_kernel(
    const float* __restrict__ x,
    const float* __restrict__ W1, const float* __restrict__ b1,
    const float* __restrict__ W2, const float* __restrict__ b2,
    __half* __restrict__ out, int n_rows) {
  int t = threadIdx.x;
  int wave = t >> 6, lane = t & 63;

  float w1reg[IN_F];
#pragma unroll
  for (int j = 0; j < IN_F; ++j) w1reg[j] = W1[lane * IN_F + j];
  float w2reg[64];
  const float4* W24 = (const float4*)(W2 + (size_t)lane * 64);
#pragma unroll
  for (int i = 0; i < 16; ++i) {
    float4 w = W24[i];
    w2reg[4 * i] = w.x; w2reg[4 * i + 1] = w.y;
    w2reg[4 * i + 2] = w.z; w2reg[4 * i + 3] = w.w;
  }
  float b1v = b1[lane], b2v = b2[lane];

  int stride = gridDim.x * WPB;
  for (int row = blockIdx.x * WPB + wave; row < n_rows; row += stride) {
    float xl = 0.0f;
    if (lane < IN_F) xl = x[(size_t)row * IN_F + lane];
    float h = b1v;
#pragma unroll
    for (int j = 0; j < IN_F; ++j) h += w1reg[j] * bcast(xl, j);
    float hid = tanhf(h);

    float o0 = b2v, o1 = 0.f, o2 = 0.f, o3 = 0.f;
#pragma unroll
    for (int i = 0; i < 64; i += 4) {
      o0 += w2reg[i]     * bcast(hid, i);
      o1 += w2reg[i + 1] * bcast(hid, i + 1);
      o2 += w2reg[i + 2] * bcast(hid, i + 2);
      o3 += w2reg[i + 3] * bcast(hid, i + 3);
    }
    out[(size_t)row * 64 + lane] = __float2half((o0 + o1) + (o2 + o3));
  }
}

// ---------------- CSR build ----------------
__global__ __launch_bounds__(256) void hist_kernel(
    const int* __restrict__ ev, const int* __restrict__ ec,
    int* __restrict__ cur_v, int* __restrict__ cur_c, int n_edges) {
  int e = blockIdx.x * 256 + threadIdx.x;
  if (e >= n_edges) return;
  atomicAdd(&cur_v[ev[e]], 1);
  atomicAdd(&cur_c[ec[e]], 1);
}

__global__ __launch_bounds__(256) void scan_blocks_kernel(
    const int* __restrict__ in, int* __restrict__ out,
    int* __restrict__ bsums, int n) {
  __shared__ int s[256];
  int t = threadIdx.x;
  int base = blockIdx.x * SCAN_EPB + t * 4;
  int v[4]; int local = 0;
#pragma unroll
  for (int j = 0; j < 4; ++j) {
    int idx = base + j;
    v[j] = (idx < n) ? in[idx] : 0;
    local += v[j];
  }
  s[t] = local;
  __syncthreads();
  for (int off = 1; off < 256; off <<= 1) {
    int val = (t >= off) ? s[t - off] : 0;
    __syncthreads();
    s[t] += val;
    __syncthreads();
  }
  int run = s[t] - local;
#pragma unroll
  for (int j = 0; j < 4; ++j) {
    int idx = base + j;
    if (idx < n) out[idx] = run;
    run += v[j];
  }
  if (t == 255) bsums[blockIdx.x] = s[255];
}

__global__ __launch_bounds__(256) void scan_sums_kernel(int* __restrict__ bsums, int nb) {
  __shared__ int s[256];
  int t = threadIdx.x;
  int base = t * 4;
  int v[4]; int local = 0;
#pragma unroll
  for (int j = 0; j < 4; ++j) {
    int idx = base + j;
    v[j] = (idx < nb) ? bsums[idx] : 0;
    local += v[j];
  }
  s[t] = local;
  __syncthreads();
  for (int off = 1; off < 256; off <<= 1) {
    int val = (t >= off) ? s[t - off] : 0;
    __syncthreads();
    s[t] += val;
    __syncthreads();
  }
  int run = s[t] - local;
#pragma unroll
  for (int j = 0; j < 4; ++j) {
    int idx = base + j;
    if (idx < nb) bsums[idx] = run;
    run += v[j];
  }
}

__global__ __launch_bounds__(256) void scan_add_kernel(
    int* __restrict__ out, const int* __restrict__ bsums, int n, int total) {
  int t = threadIdx.x;
  int base = blockIdx.x * SCAN_EPB + t * 4;
  int add = bsums[blockIdx.x];
#pragma unroll
  for (int j = 0; j < 4; ++j) {
    int idx = base + j;
    if (idx < n) out[idx] += add;
  }
  if (blockIdx.x == 0 && t == 0) out[n] = total;
}

__global__ __launch_bounds__(256) void place_kernel(
    const int* __restrict__ ev, const int* __restrict__ ec,
    const int* __restrict__ rp_v, const int* __restrict__ rp_c,
    int* __restrict__ cur_v, int* __restrict__ cur_c,
    int* __restrict__ esrc_v, int* __restrict__ esrc_c, int n_edges) {
  int e = blockIdx.x * 256 + threadIdx.x;
  if (e >= n_edges) return;
  int v = ev[e], c = ec[e];
  int pc = rp_c[c] + atomicAdd(&cur_c[c], 1);
  esrc_c[pc] = v;
  int pv = rp_v[v] + atomicAdd(&cur_v[v], 1);
  esrc_v[pv] = c;
}

// ---------------- fused aggregate + linear + tanh (+ optional readout) ----------------
// One dest row per wave. h rows in f16 (128 B). Gather: lanes 0-31 read row esrc[p],
// lanes 32-63 read row esrc[p+1], half2 per lane -> one dword load covers 2 edges.
// W in per-lane VGPRs; broadcasts via v_readlane. No LDS.
template<bool RO>
__global__ __launch_bounds__(256, 4) void fused_update_kernel(
    __half* __restrict__ hdst, const __half* __restrict__ hsrc,
    const int* __restrict__ rp, const int* __restrict__ esrc,
    const float* __restrict__ W, const float* __restrict__ b,
    const float* __restrict__ Wro, const float* __restrict__ bro,
    float* __restrict__ scores, int n_rows) {
  int t = threadIdx.x;
  int wave = t >> 6, lane = t & 63;
  int half_sel = lane >> 5;   // 0 for lanes 0-31, 1 for lanes 32-63
  int pair = lane & 31;       // feature-pair index within row

  float wreg[64];  // lane o holds W[o][0..63]
  const float4* W4 = (const float4*)(W + (size_t)lane * 64);
#pragma unroll
  for (int i = 0; i < 16; ++i) {
    float4 w = W4[i];
    wreg[4 * i] = w.x; wreg[4 * i + 1] = w.y;
    wreg[4 * i + 2] = w.z; wreg[4 * i + 3] = w.w;
  }
  float bv = b[lane];
  float wrov = RO ? Wro[lane] : 0.0f;
  float brov = RO ? bro[0] : 0.0f;

  const __half2* hsrc2 = (const __half2*)hsrc;

  int stride = gridDim.x * WPB;
  for (int row = blockIdx.x * WPB + wave; row < n_rows; row += stride) {
    int p = rp[row], end = rp[row + 1];
    float deg = (float)(end - p);
    float ax = 0.f, ay = 0.f;

    // 8 edges per iter: 4 dual-row loads in flight
    for (; p + 8 <= end; p += 8) {
      int s0 = esrc[p     + half_sel];
      int s1 = esrc[p + 2 + half_sel];
      int s2 = esrc[p + 4 + half_sel];
      int s3 = esrc[p + 6 + half_sel];
      float2 f0 = __half22float2(hsrc2[(size_t)s0 * 32 + pair]);
      float2 f1 = __half22float2(hsrc2[(size_t)s1 * 32 + pair]);
      float2 f2 = __half22float2(hsrc2[(size_t)s2 * 32 + pair]);
      float2 f3 = __half22float2(hsrc2[(size_t)s3 * 32 + pair]);
      ax += (f0.x + f1.x) + (f2.x + f3.x);
      ay += (f0.y + f1.y) + (f2.y + f3.y);
    }
    for (; p + 2 <= end; p += 2) {
      int s = esrc[p + half_sel];
      float2 f = __half22float2(hsrc2[(size_t)s * 32 + pair]);
      ax += f.x; ay += f.y;
    }
    if (p < end) {  // odd tail: only lower half contributes
      int s = esrc[p];
      float2 f = __half22float2(hsrc2[(size_t)s * 32 + pair]);
      if (half_sel == 0) { ax += f.x; ay += f.y; }
    }
    // combine the two lane-halves: lanes k and k+32 both end with pair sums
    ax += __shfl_xor(ax, 32, 64);
    ay += __shfl_xor(ay, 32, 64);

    float v0 = __half2float(hdst[(size_t)row * 64 + lane]) + bv * deg;
    float v1 = 0.f, v2 = 0.f, v3 = 0.f;
#pragma unroll
    for (int j = 0; j < 32; j += 2) {
      v0 += wreg[2 * j]     * bcast(ax, j);
      v1 += wreg[2 * j + 1] * bcast(ay, j);
      v2 += wreg[2 * j + 2] * bcast(ax, j + 1);
      v3 += wreg[2 * j + 3] * bcast(ay, j + 1);
    }
    float hv = tanhf((v0 + v1) + (v2 + v3));
    if (RO) {
      float rv = hv * wrov;
#pragma unroll
      for (int off = 32; off > 0; off >>= 1) rv += __shfl_xor(rv, off, 64);
      if (lane == 0) scores[row] = rv + brov;
    } else {
      hdst[(size_t)row * 64 + lane] = __float2half(hv);
    }
  }
}

static inline int rowgrid(int n) {
  int want = (n + WPB - 1) / WPB;
  return want < 2048 ? want : 2048;
}

extern "C" void kernel_launch(void* const* d_in, const int* in_sizes, int n_in,
                              void* d_out, int out_size, void* d_ws, size_t ws_size,
                              hipStream_t stream) {
  const float* vf    = (const float*)d_in[0];
  const float* cf    = (const float*)d_in[1];
  const int*   ev    = (const int*)d_in[2];
  const int*   ec    = (const int*)d_in[3];
  const float* W_ve1 = (const float*)d_in[4];
  const float* b_ve1 = (const float*)d_in[5];
  const float* W_ve2 = (const float*)d_in[6];
  const float* b_ve2 = (const float*)d_in[7];
  const float* W_ce1 = (const float*)d_in[8];
  const float* b_ce1 = (const float*)d_in[9];
  const float* W_ce2 = (const float*)d_in[10];
  const float* b_ce2 = (const float*)d_in[11];
  const float* W_v2c = (const float*)d_in[12];
  const float* b_v2c = (const float*)d_in[13];
  const float* W_c2v = (const float*)d_in[14];
  const float* b_c2v = (const float*)d_in[15];
  const float* W_ro  = (const float*)d_in[16];
  const float* b_ro  = (const float*)d_in[17];

  const int n_vars  = in_sizes[0] / 7;
  const int n_cons  = in_sizes[1] / 5;
  const int n_edges = in_sizes[2];
  const int R       = in_sizes[12] / (64 * 64);

  char* p = (char*)d_ws;
  __half* h_var = (__half*)p; p += (size_t)n_vars * 64 * 2;
  __half* h_con = (__half*)p; p += (size_t)n_cons * 64 * 2;
  int*   rp_v   = (int*)p;   p += (size_t)(n_vars + 1) * 4;
  int*   rp_c   = (int*)p;   p += (size_t)(n_cons + 1) * 4;
  int*   cur_v  = (int*)p;   p += (size_t)n_vars * 4;
  int*   cur_c  = (int*)p;   p += (size_t)n_cons * 4;
  int*   esrc_v = (int*)p;   p += (size_t)n_edges * 4;
  int*   esrc_c = (int*)p;   p += (size_t)n_edges * 4;
  int*   bsums  = (int*)p;   p += 1024 * 4;

  const int nb_v = (n_vars + SCAN_EPB - 1) / SCAN_EPB;
  const int nb_c = (n_cons + SCAN_EPB - 1) / SCAN_EPB;

  hipMemsetAsync(cur_v, 0, (size_t)n_vars * 4, stream);
  hipMemsetAsync(cur_c, 0, (size_t)n_cons * 4, stream);
  hist_kernel<<<(n_edges + 255) / 256, 256, 0, stream>>>(ev, ec, cur_v, cur_c, n_edges);

  scan_blocks_kernel<<<nb_v, 256, 0, stream>>>(cur_v, rp_v, bsums, n_vars);
  scan_sums_kernel<<<1, 256, 0, stream>>>(bsums, nb_v);
  scan_add_kernel<<<nb_v, 256, 0, stream>>>(rp_v, bsums, n_vars, n_edges);
  scan_blocks_kernel<<<nb_c, 256, 0, stream>>>(cur_c, rp_c, bsums, n_cons);
  scan_sums_kernel<<<1, 256, 0, stream>>>(bsums, nb_c);
  scan_add_kernel<<<nb_c, 256, 0, stream>>>(rp_c, bsums, n_cons, n_edges);

  hipMemsetAsync(cur_v, 0, (size_t)n_vars * 4, stream);
  hipMemsetAsync(cur_c, 0, (size_t)n_cons * 4, stream);
  place_kernel<<<(n_edges + 255) / 256, 256, 0, stream>>>(
      ev, ec, rp_v, rp_c, cur_v, cur_c, esrc_v, esrc_c, n_edges);

  encoder_kernel<7><<<rowgrid(n_vars), 256, 0, stream>>>(
      vf, W_ve1, b_ve1, W_ve2, b_ve2, h_var, n_vars);
  encoder_kernel<5><<<rowgrid(n_cons), 256, 0, stream>>>(
      cf, W_ce1, b_ce1, W_ce2, b_ce2, h_con, n_cons);

  for (int r = 0; r < R; ++r) {
    fused_update_kernel<false><<<rowgrid(n_cons), 256, 0, stream>>>(
        h_con, h_var, rp_c, esrc_c,
        W_v2c + (size_t)r * 64 * 64, b_v2c + (size_t)r * 64,
        nullptr, nullptr, nullptr, n_cons);
    if (r == R - 1) {
      fused_update_kernel<true><<<rowgrid(n_vars), 256, 0, stream>>>(
          h_var, h_con, rp_v, esrc_v,
          W_c2v + (size_t)r * 64 * 64, b_c2v + (size_t)r * 64,
          W_ro, b_ro, (float*)d_out, n_vars);
    } else {
      fused_update_kernel<false><<<rowgrid(n_vars), 256, 0, stream>>>(
          h_var, h_con, rp_v, esrc_v,
          W_c2v + (size_t)r * 64 * 64, b_c2v + (size_t)r * 64,
          nullptr, nullptr, nullptr, n_vars);
    }
  }
}

// Round 8
// 942.101 us; speedup vs baseline: 2.3883x; 1.0158x over previous
//
#include <hip/hip_runtime.h>
#include <hip/hip_bf16.h>
#include <hip/hip_fp16.h>

#define WPB 4          // waves per block (256 threads)
#define SCAN_EPB 1024  // elements per scan block (256 thr x 4)
#define PLACE_NB 4     // sequential destination-range passes for CSR placement

__device__ __forceinline__ float bcast(float v, int i) {
  return __builtin_bit_cast(float, __builtin_amdgcn_readlane(__builtin_bit_cast(int, v), i));
}

// ---------------- encoders ----------------
// out = tanh(x @ W1^T + b1) @ W2^T + b2. One row per wave; W in VGPRs; f16 output.
template<int IN_F>
__global__ __launch_bounds__(256, 4) void encoder_kernel(
    const float* __restrict__ x,
    const float* __restrict__ W1, const float* __restrict__ b1,
    const float* __restrict__ W2, const float* __restrict__ b2,
    __half* __restrict__ out, int n_rows) {
  int t = threadIdx.x;
  int wave = t >> 6, lane = t & 63;

  float w1reg[IN_F];
#pragma unroll
  for (int j = 0; j < IN_F; ++j) w1reg[j] = W1[lane * IN_F + j];
  float w2reg[64];
  const float4* W24 = (const float4*)(W2 + (size_t)lane * 64);
#pragma unroll
  for (int i = 0; i < 16; ++i) {
    float4 w = W24[i];
    w2reg[4 * i] = w.x; w2reg[4 * i + 1] = w.y;
    w2reg[4 * i + 2] = w.z; w2reg[4 * i + 3] = w.w;
  }
  float b1v = b1[lane], b2v = b2[lane];

  int stride = gridDim.x * WPB;
  for (int row = blockIdx.x * WPB + wave; row < n_rows; row += stride) {
    float xl = 0.0f;
    if (lane < IN_F) xl = x[(size_t)row * IN_F + lane];
    float h = b1v;
#pragma unroll
    for (int j = 0; j < IN_F; ++j) h += w1reg[j] * bcast(xl, j);
    float hid = tanhf(h);

    float o0 = b2v, o1 = 0.f, o2 = 0.f, o3 = 0.f;
#pragma unroll
    for (int i = 0; i < 64; i += 4) {
      o0 += w2reg[i]     * bcast(hid, i);
      o1 += w2reg[i + 1] * bcast(hid, i + 1);
      o2 += w2reg[i + 2] * bcast(hid, i + 2);
      o3 += w2reg[i + 3] * bcast(hid, i + 3);
    }
    out[(size_t)row * 64 + lane] = __float2half((o0 + o1) + (o2 + o3));
  }
}

// ---------------- CSR build ----------------
__global__ __launch_bounds__(256) void hist_kernel(
    const int* __restrict__ ev, const int* __restrict__ ec,
    int* __restrict__ cur_v, int* __restrict__ cur_c, int n_edges) {
  int e = blockIdx.x * 256 + threadIdx.x;
  if (e >= n_edges) return;
  atomicAdd(&cur_v[ev[e]], 1);
  atomicAdd(&cur_c[ec[e]], 1);
}

__global__ __launch_bounds__(256) void scan_blocks_kernel(
    const int* __restrict__ in, int* __restrict__ out,
    int* __restrict__ bsums, int n) {
  __shared__ int s[256];
  int t = threadIdx.x;
  int base = blockIdx.x * SCAN_EPB + t * 4;
  int v[4]; int local = 0;
#pragma unroll
  for (int j = 0; j < 4; ++j) {
    int idx = base + j;
    v[j] = (idx < n) ? in[idx] : 0;
    local += v[j];
  }
  s[t] = local;
  __syncthreads();
  for (int off = 1; off < 256; off <<= 1) {
    int val = (t >= off) ? s[t - off] : 0;
    __syncthreads();
    s[t] += val;
    __syncthreads();
  }
  int run = s[t] - local;
#pragma unroll
  for (int j = 0; j < 4; ++j) {
    int idx = base + j;
    if (idx < n) out[idx] = run;
    run += v[j];
  }
  if (t == 255) bsums[blockIdx.x] = s[255];
}

__global__ __launch_bounds__(256) void scan_sums_kernel(int* __restrict__ bsums, int nb) {
  __shared__ int s[256];
  int t = threadIdx.x;
  int base = t * 4;
  int v[4]; int local = 0;
#pragma unroll
  for (int j = 0; j < 4; ++j) {
    int idx = base + j;
    v[j] = (idx < nb) ? bsums[idx] : 0;
    local += v[j];
  }
  s[t] = local;
  __syncthreads();
  for (int off = 1; off < 256; off <<= 1) {
    int val = (t >= off) ? s[t - off] : 0;
    __syncthreads();
    s[t] += val;
    __syncthreads();
  }
  int run = s[t] - local;
#pragma unroll
  for (int j = 0; j < 4; ++j) {
    int idx = base + j;
    if (idx < nb) bsums[idx] = run;
    run += v[j];
  }
}

__global__ __launch_bounds__(256) void scan_add_kernel(
    int* __restrict__ out, const int* __restrict__ bsums, int n, int total) {
  int t = threadIdx.x;
  int base = blockIdx.x * SCAN_EPB + t * 4;
  int add = bsums[blockIdx.x];
#pragma unroll
  for (int j = 0; j < 4; ++j) {
    int idx = base + j;
    if (idx < n) out[idx] += add;
  }
  if (blockIdx.x == 0 && t == 0) out[n] = total;
}

// Range-partitioned placement: only edges whose destination lies in this
// launch's range are written. Sequential launches keep the scattered-write
// working set ~1.2 MB/side -> L2-local -> no partial-line write amplification.
__global__ __launch_bounds__(256) void place_range_kernel(
    const int* __restrict__ ev, const int* __restrict__ ec,
    const int* __restrict__ rp_v, const int* __restrict__ rp_c,
    int* __restrict__ cur_v, int* __restrict__ cur_c,
    int* __restrict__ esrc_v, int* __restrict__ esrc_c, int n_edges,
    int vlo, int vhi, int clo, int chi) {
  int stride = gridDim.x * 256;
  for (int e = blockIdx.x * 256 + threadIdx.x; e < n_edges; e += stride) {
    int v = ev[e], c = ec[e];
    if (c >= clo && c < chi) {
      int pc = rp_c[c] + atomicAdd(&cur_c[c], 1);
      esrc_c[pc] = v;
    }
    if (v >= vlo && v < vhi) {
      int pv = rp_v[v] + atomicAdd(&cur_v[v], 1);
      esrc_v[pv] = c;
    }
  }
}

// ---------------- fused aggregate + linear + tanh (+ optional readout) ----------------
// One dest row per wave. h rows in f16 (128 B). Gather: lanes 0-31 read row esrc[p],
// lanes 32-63 read row esrc[p+1], half2 per lane -> one dword load covers 2 edges.
// W in per-lane VGPRs; broadcasts via v_readlane. No LDS.
template<bool RO>
__global__ __launch_bounds__(256, 4) void fused_update_kernel(
    __half* __restrict__ hdst, const __half* __restrict__ hsrc,
    const int* __restrict__ rp, const int* __restrict__ esrc,
    const float* __restrict__ W, const float* __restrict__ b,
    const float* __restrict__ Wro, const float* __restrict__ bro,
    float* __restrict__ scores, int n_rows) {
  int t = threadIdx.x;
  int wave = t >> 6, lane = t & 63;
  int half_sel = lane >> 5;   // 0 for lanes 0-31, 1 for lanes 32-63
  int pair = lane & 31;       // feature-pair index within row

  float wreg[64];  // lane o holds W[o][0..63]
  const float4* W4 = (const float4*)(W + (size_t)lane * 64);
#pragma unroll
  for (int i = 0; i < 16; ++i) {
    float4 w = W4[i];
    wreg[4 * i] = w.x; wreg[4 * i + 1] = w.y;
    wreg[4 * i + 2] = w.z; wreg[4 * i + 3] = w.w;
  }
  float bv = b[lane];
  float wrov = RO ? Wro[lane] : 0.0f;
  float brov = RO ? bro[0] : 0.0f;

  const __half2* hsrc2 = (const __half2*)hsrc;

  int stride = gridDim.x * WPB;
  for (int row = blockIdx.x * WPB + wave; row < n_rows; row += stride) {
    int p = rp[row], end = rp[row + 1];
    float deg = (float)(end - p);
    float ax = 0.f, ay = 0.f;

    // 8 edges per iter: 4 dual-row loads in flight
    for (; p + 8 <= end; p += 8) {
      int s0 = esrc[p     + half_sel];
      int s1 = esrc[p + 2 + half_sel];
      int s2 = esrc[p + 4 + half_sel];
      int s3 = esrc[p + 6 + half_sel];
      float2 f0 = __half22float2(hsrc2[(size_t)s0 * 32 + pair]);
      float2 f1 = __half22float2(hsrc2[(size_t)s1 * 32 + pair]);
      float2 f2 = __half22float2(hsrc2[(size_t)s2 * 32 + pair]);
      float2 f3 = __half22float2(hsrc2[(size_t)s3 * 32 + pair]);
      ax += (f0.x + f1.x) + (f2.x + f3.x);
      ay += (f0.y + f1.y) + (f2.y + f3.y);
    }
    for (; p + 2 <= end; p += 2) {
      int s = esrc[p + half_sel];
      float2 f = __half22float2(hsrc2[(size_t)s * 32 + pair]);
      ax += f.x; ay += f.y;
    }
    if (p < end) {  // odd tail: only lower half contributes
      int s = esrc[p];
      float2 f = __half22float2(hsrc2[(size_t)s * 32 + pair]);
      if (half_sel == 0) { ax += f.x; ay += f.y; }
    }
    // combine the two lane-halves: lanes k and k+32 both end with pair sums
    ax += __shfl_xor(ax, 32, 64);
    ay += __shfl_xor(ay, 32, 64);

    float v0 = __half2float(hdst[(size_t)row * 64 + lane]) + bv * deg;
    float v1 = 0.f, v2 = 0.f, v3 = 0.f;
#pragma unroll
    for (int j = 0; j < 32; j += 2) {
      v0 += wreg[2 * j]     * bcast(ax, j);
      v1 += wreg[2 * j + 1] * bcast(ay, j);
      v2 += wreg[2 * j + 2] * bcast(ax, j + 1);
      v3 += wreg[2 * j + 3] * bcast(ay, j + 1);
    }
    float hv = tanhf((v0 + v1) + (v2 + v3));
    if (RO) {
      float rv = hv * wrov;
#pragma unroll
      for (int off = 32; off > 0; off >>= 1) rv += __shfl_xor(rv, off, 64);
      if (lane == 0) scores[row] = rv + brov;
    } else {
      hdst[(size_t)row * 64 + lane] = __float2half(hv);
    }
  }
}

static inline int rowgrid(int n) {
  int want = (n + WPB - 1) / WPB;
  return want < 2048 ? want : 2048;
}

extern "C" void kernel_launch(void* const* d_in, const int* in_sizes, int n_in,
                              void* d_out, int out_size, void* d_ws, size_t ws_size,
                              hipStream_t stream) {
  const float* vf    = (const float*)d_in[0];
  const float* cf    = (const float*)d_in[1];
  const int*   ev    = (const int*)d_in[2];
  const int*   ec    = (const int*)d_in[3];
  const float* W_ve1 = (const float*)d_in[4];
  const float* b_ve1 = (const float*)d_in[5];
  const float* W_ve2 = (const float*)d_in[6];
  const float* b_ve2 = (const float*)d_in[7];
  const float* W_ce1 = (const float*)d_in[8];
  const float* b_ce1 = (const float*)d_in[9];
  const float* W_ce2 = (const float*)d_in[10];
  const float* b_ce2 = (const float*)d_in[11];
  const float* W_v2c = (const float*)d_in[12];
  const float* b_v2c = (const float*)d_in[13];
  const float* W_c2v = (const float*)d_in[14];
  const float* b_c2v = (const float*)d_in[15];
  const float* W_ro  = (const float*)d_in[16];
  const float* b_ro  = (const float*)d_in[17];

  const int n_vars  = in_sizes[0] / 7;
  const int n_cons  = in_sizes[1] / 5;
  const int n_edges = in_sizes[2];
  const int R       = in_sizes[12] / (64 * 64);

  char* p = (char*)d_ws;
  __half* h_var = (__half*)p; p += (size_t)n_vars * 64 * 2;
  __half* h_con = (__half*)p; p += (size_t)n_cons * 64 * 2;
  int*   rp_v   = (int*)p;   p += (size_t)(n_vars + 1) * 4;
  int*   rp_c   = (int*)p;   p += (size_t)(n_cons + 1) * 4;
  int*   cur_v  = (int*)p;   p += (size_t)n_vars * 4;
  int*   cur_c  = (int*)p;   p += (size_t)n_cons * 4;
  int*   esrc_v = (int*)p;   p += (size_t)n_edges * 4;
  int*   esrc_c = (int*)p;   p += (size_t)n_edges * 4;
  int*   bsums  = (int*)p;   p += 1024 * 4;

  const int nb_v = (n_vars + SCAN_EPB - 1) / SCAN_EPB;
  const int nb_c = (n_cons + SCAN_EPB - 1) / SCAN_EPB;

  hipMemsetAsync(cur_v, 0, (size_t)n_vars * 4, stream);
  hipMemsetAsync(cur_c, 0, (size_t)n_cons * 4, stream);
  hist_kernel<<<(n_edges + 255) / 256, 256, 0, stream>>>(ev, ec, cur_v, cur_c, n_edges);

  scan_blocks_kernel<<<nb_v, 256, 0, stream>>>(cur_v, rp_v, bsums, n_vars);
  scan_sums_kernel<<<1, 256, 0, stream>>>(bsums, nb_v);
  scan_add_kernel<<<nb_v, 256, 0, stream>>>(rp_v, bsums, n_vars, n_edges);
  scan_blocks_kernel<<<nb_c, 256, 0, stream>>>(cur_c, rp_c, bsums, n_cons);
  scan_sums_kernel<<<1, 256, 0, stream>>>(bsums, nb_c);
  scan_add_kernel<<<nb_c, 256, 0, stream>>>(rp_c, bsums, n_cons, n_edges);

  hipMemsetAsync(cur_v, 0, (size_t)n_vars * 4, stream);
  hipMemsetAsync(cur_c, 0, (size_t)n_cons * 4, stream);
  {
    const int vrng = (n_vars + PLACE_NB - 1) / PLACE_NB;
    const int crng = (n_cons + PLACE_NB - 1) / PLACE_NB;
    for (int bpass = 0; bpass < PLACE_NB; ++bpass) {
      int vlo = bpass * vrng, vhi = vlo + vrng;
      int clo = bpass * crng, chi = clo + crng;
      place_range_kernel<<<1024, 256, 0, stream>>>(
          ev, ec, rp_v, rp_c, cur_v, cur_c, esrc_v, esrc_c, n_edges,
          vlo, vhi, clo, chi);
    }
  }

  encoder_kernel<7><<<rowgrid(n_vars), 256, 0, stream>>>(
      vf, W_ve1, b_ve1, W_ve2, b_ve2, h_var, n_vars);
  encoder_kernel<5><<<rowgrid(n_cons), 256, 0, stream>>>(
      cf, W_ce1, b_ce1, W_ce2, b_ce2, h_con, n_cons);

  for (int r = 0; r < R; ++r) {
    fused_update_kernel<false><<<rowgrid(n_cons), 256, 0, stream>>>(
        h_con, h_var, rp_c, esrc_c,
        W_v2c + (size_t)r * 64 * 64, b_v2c + (size_t)r * 64,
        nullptr, nullptr, nullptr, n_cons);
    if (r == R - 1) {
      fused_update_kernel<true><<<rowgrid(n_vars), 256, 0, stream>>>(
          h_var, h_con, rp_v, esrc_v,
          W_c2v + (size_t)r * 64 * 64, b_c2v + (size_t)r * 64,
          W_ro, b_ro, (float*)d_out, n_vars);
    } else {
      fused_update_kernel<false><<<rowgrid(n_vars), 256, 0, stream>>>(
          h_var, h_con, rp_v, esrc_v,
          W_c2v + (size_t)r * 64 * 64, b_c2v + (size_t)r * 64,
          nullptr, nullptr, nullptr, n_vars);
    }
  }
}